// Round 6
// baseline (238.531 us; speedup 1.0000x reference)
//
#include <hip/hip_runtime.h>

typedef __bf16 bf16;
typedef __bf16 bf16x8_t __attribute__((ext_vector_type(8)));
typedef __bf16 bf16x4_t __attribute__((ext_vector_type(4)));
typedef float f32x4_t __attribute__((ext_vector_type(4)));

#define S_ 2048
#define E_ 1024
#define HD 64
#define LOG2E 1.4426950408889634f
#define QSCALE (0.125f * LOG2E)   // 1/sqrt(64) * log2(e), folded into Q

// async global->LDS, 16B per lane; LDS dest is wave-uniform base + lane*16
__device__ __forceinline__ void gl_lds16(const bf16* g, bf16* l) {
  __builtin_amdgcn_global_load_lds(
      (const __attribute__((address_space(1))) unsigned int*)g,
      (__attribute__((address_space(3))) unsigned int*)l, 16, 0, 0);
}

__device__ __forceinline__ f32x4_t vmax4(f32x4_t a, f32x4_t b) {
  f32x4_t r;
  r[0] = fmaxf(a[0], b[0]); r[1] = fmaxf(a[1], b[1]);
  r[2] = fmaxf(a[2], b[2]); r[3] = fmaxf(a[3], b[3]);
  return r;
}

// ---------- fused prep: x fp32->bf16, W_attn^T, W_proj^T (one launch) ----------
__device__ __forceinline__ void transpose_tile(const float* __restrict__ in,
                                               bf16* __restrict__ out,
                                               int R, int C, int bx, int by,
                                               float tile[32][33]) {
  int c0 = bx * 32, r0 = by * 32;
  int tx = threadIdx.x & 31, ty = threadIdx.x >> 5;
#pragma unroll
  for (int i = 0; i < 32; i += 8)
    tile[ty + i][tx] = in[(size_t)(r0 + ty + i) * C + c0 + tx];
  __syncthreads();
#pragma unroll
  for (int i = 0; i < 32; i += 8)
    out[(size_t)(c0 + ty + i) * R + r0 + tx] = (bf16)tile[tx][ty + i];
}

__global__ void prep(const float* __restrict__ x, bf16* __restrict__ xb,
                     const float* __restrict__ Wa, bf16* __restrict__ Wat,
                     const float* __restrict__ Wp, bf16* __restrict__ Wpt) {
  __shared__ float tile[32][33];
  int bid = blockIdx.x;
  if (bid < 8192) {                       // cvt: 8192*1024 fp32 -> bf16
    int i = (bid * 256 + threadIdx.x) * 4;
    float4 v = *(const float4*)(x + i);
    bf16x4_t o = { (bf16)v.x, (bf16)v.y, (bf16)v.z, (bf16)v.w };
    *(bf16x4_t*)(xb + i) = o;
  } else if (bid < 8192 + 3072) {         // W_attn [1024][3072] -> [3072][1024]
    int f = bid - 8192;
    transpose_tile(Wa, Wat, 1024, 3072, f % 96, f / 96, tile);
  } else {                                // W_proj [1024][1024] -> [1024][1024]^T
    int f = bid - 11264;
    transpose_tile(Wp, Wpt, 1024, 1024, f % 32, f / 32, tile);
  }
}

// ---------- 128x128-tile GEMM, BK=64, global_load_lds staging, XOR-swizzled LDS ----
// MODE 0: QKV epilogue (scatter to Q scaled, K, Vt transposed). MODE 1: proj fp32 out.
template <int MODE>
__global__ __launch_bounds__(256, 2)
void gemm128(const bf16* __restrict__ A, const bf16* __restrict__ Bt,
             const float* __restrict__ bias,
             bf16* __restrict__ Q, bf16* __restrict__ K, bf16* __restrict__ Vt,
             float* __restrict__ Out) {
  __shared__ __align__(16) bf16 As[128 * 64];
  __shared__ __align__(16) bf16 Bs[128 * 64];
  const int tid = threadIdx.x;
  const int wave = tid >> 6, lane = tid & 63;
  const int quad = lane >> 4, l16 = lane & 15;
  const int wm = wave >> 1, wn = wave & 1;
  const int bm = blockIdx.x, bn = blockIdx.y;

  f32x4_t acc[4][4];
#pragma unroll
  for (int i = 0; i < 4; i++)
#pragma unroll
    for (int j = 0; j < 4; j++) acc[i][j] = (f32x4_t){0.f, 0.f, 0.f, 0.f};

  for (int k0 = 0; k0 < 1024; k0 += 64) {
    __syncthreads();
    // stage 16KB A + 16KB B; swizzle source so LDS chunk (row, c) holds
    // global chunk (row, c ^ (row&7)) -> reads are 2-way max
#pragma unroll
    for (int it = 0; it < 4; it++) {
      int id = it * 256 + tid;
      int row = id >> 3, c = id & 7;
      int sc = (c ^ (row & 7)) * 8;
      gl_lds16(A + (size_t)(bm * 128 + row) * 1024 + k0 + sc, As + id * 8);
      gl_lds16(Bt + (size_t)(bn * 128 + row) * 1024 + k0 + sc, Bs + id * 8);
    }
    __syncthreads();
#pragma unroll
    for (int ks = 0; ks < 2; ks++) {
      bf16x8_t af[4], bfr[4];
#pragma unroll
      for (int i = 0; i < 4; i++) {
        int row = wm * 64 + i * 16 + l16;
        af[i] = *(const bf16x8_t*)&As[row * 64 + (((ks * 4 + quad) ^ (row & 7)) * 8)];
      }
#pragma unroll
      for (int j = 0; j < 4; j++) {
        int row = wn * 64 + j * 16 + l16;
        bfr[j] = *(const bf16x8_t*)&Bs[row * 64 + (((ks * 4 + quad) ^ (row & 7)) * 8)];
      }
#pragma unroll
      for (int i = 0; i < 4; i++)
#pragma unroll
        for (int j = 0; j < 4; j++)
          acc[i][j] = __builtin_amdgcn_mfma_f32_16x16x32_bf16(af[i], bfr[j], acc[i][j], 0, 0, 0);
    }
  }

  if (MODE == 0) {
    // n decides q/k/v. Q: [bh][s][64] scaled by QSCALE. K: [bh][s][64]. V: [bh][64][s].
#pragma unroll
    for (int j = 0; j < 4; j++) {
      int n_g = bn * 128 + wn * 64 + j * 16 + l16;
      float bv = bias[n_g];
      int which = n_g >> 10;
      int cc = n_g & 1023;
      int hh = cc >> 6, dd = cc & 63;
#pragma unroll
      for (int i = 0; i < 4; i++) {
        int m0 = bm * 128 + wm * 64 + i * 16 + quad * 4;
        int bb = m0 >> 11, ss0 = m0 & 2047;
        int bhn = bb * 16 + hh;
        if (which == 2) {
          bf16x4_t pk;
#pragma unroll
          for (int r = 0; r < 4; r++) pk[r] = (bf16)(acc[i][j][r] + bv);
          *(bf16x4_t*)&Vt[((size_t)bhn * 64 + dd) * 2048 + ss0] = pk;
        } else {
          bf16* dst = (which == 0) ? Q : K;
          float scl = (which == 0) ? QSCALE : 1.f;
#pragma unroll
          for (int r = 0; r < 4; r++)
            dst[((size_t)bhn * 2048 + ss0 + r) * 64 + dd] = (bf16)((acc[i][j][r] + bv) * scl);
        }
      }
    }
  } else {
#pragma unroll
    for (int j = 0; j < 4; j++) {
      int n_g = bn * 128 + wn * 64 + j * 16 + l16;
      float bv = bias[n_g];
#pragma unroll
      for (int i = 0; i < 4; i++) {
        int m0 = bm * 128 + wm * 64 + i * 16 + quad * 4;
#pragma unroll
        for (int r = 0; r < 4; r++)
          Out[(size_t)(m0 + r) * 1024 + n_g] = acc[i][j][r] + bv;
      }
    }
  }
}

// ---------- Flash attention, S^T formulation, software-pipelined, P-in-register ----
// Round-1 pipeline (74.8us measured): 4 waves; K/V double-buffered (now 64KB dynamic
// LDS, 2 blocks/CU); stage(kb+1) issued BEFORE compute(kb); single __syncthreads per
// tile. Wave owns 32 q rows. S^T = K*Q^T (lane holds S^T[k][q]).
// Round-6: NO P LDS round-trip. MFMA is invariant under a permutation pi of the
// reduction index applied to both operands. Choose pi(quad,j) =
// (2f+(j>>2))*16 + quad*4 + (j&3): the PV B-fragment is then the lane's OWN
// sacc values (cast to bf16) -- zero cross-lane traffic -- and the A-side (V)
// permutation is absorbed into the LDS read addresses (two ds_read_b64 per
// fragment: s-groups g=4f+(quad>>1) and g+2, half (quad&1)).
// Also: softmax max/sum tree-reduced (dep depth 31 -> ~9).
__global__ __launch_bounds__(256, 2)
void attn_kernel(const bf16* __restrict__ Q, const bf16* __restrict__ K,
                 const bf16* __restrict__ Vt, bf16* __restrict__ O) {
  extern __shared__ __align__(16) bf16 smem[];
  bf16* Ks = smem;              // [2][128*64]  2x16KB  [k][d] swizzled
  bf16* Vs = smem + 16384;      // [2][64*128]  2x16KB  [d][s] swizzled
  const int tid = threadIdx.x;
  const int wave = tid >> 6, lane = tid & 63;
  const int quad = lane >> 4, l16 = lane & 15;
  const int pid = blockIdx.x, bh = blockIdx.y;
  const int b = bh >> 4, h = bh & 15;

  const bf16* Qg = Q + (size_t)bh * S_ * HD;
  const bf16* Kg = K + (size_t)bh * S_ * HD;
  const bf16* Vg = Vt + (size_t)bh * HD * S_;

  auto stage = [&](int c, int kb) {
    const bf16* Ksrc = Kg + (size_t)kb * 128 * HD;
    const bf16* Vsrc = Vg + kb * 128;
    bf16* Kd = Ks + c * 8192;
    bf16* Vd = Vs + c * 8192;
#pragma unroll
    for (int it = 0; it < 4; it++) {
      int id = it * 256 + tid;
      {
        int row = id >> 3, cc = id & 7;
        gl_lds16(Ksrc + row * 64 + ((cc ^ (row & 7)) * 8), Kd + id * 8);
      }
      {
        int d = id >> 4, cc = id & 15;
        gl_lds16(Vsrc + (size_t)d * S_ + ((cc ^ (d & 7)) * 8), Vd + id * 8);
      }
    }
  };

  int cur = 0;
  stage(0, 0);  // prologue: tile 0

  for (int qi = 0; qi < 2; qi++) {
    const int qb = qi ? (15 - pid) : pid;
    // Q fragments (B-operand): n = q row (l16), k = d
    bf16x8_t qf[2][2];
#pragma unroll
    for (int ni = 0; ni < 2; ni++)
#pragma unroll
      for (int ks = 0; ks < 2; ks++)
        qf[ni][ks] = *(const bf16x8_t*)(Qg +
            (size_t)(qb * 128 + wave * 32 + ni * 16 + l16) * HD + ks * 32 + quad * 8);

    f32x4_t o[4][2];
#pragma unroll
    for (int mi = 0; mi < 4; mi++)
#pragma unroll
      for (int ni = 0; ni < 2; ni++) o[mi][ni] = (f32x4_t){0.f, 0.f, 0.f, 0.f};
    float m_[2] = {-1e30f, -1e30f}, l_[2] = {0.f, 0.f};

    if (qi == 0) __syncthreads();  // prologue stage complete (qi=1's tile 0 is
                                   // covered by qi=0's last end-of-iter barrier)

    for (int kb = 0; kb <= qb; kb++) {
      // issue next tile's loads FIRST -> in flight under the whole compute phase
      if (kb < qb) stage(cur ^ 1, kb + 1);
      else if (qi == 0) stage(cur ^ 1, 0);  // prefetch qi=1's tile 0 (qb-independent)

      const bf16* Kc = Ks + cur * 8192;
      const bf16* Vc = Vs + cur * 8192;

      // S^T = K · Q^T : lane holds S^T[k = mi*16+quad*4+r][q = ni*16+l16]
      f32x4_t sacc[8][2];
#pragma unroll
      for (int mi = 0; mi < 8; mi++)
#pragma unroll
        for (int ni = 0; ni < 2; ni++) sacc[mi][ni] = (f32x4_t){0.f, 0.f, 0.f, 0.f};
#pragma unroll
      for (int ks = 0; ks < 2; ks++)
#pragma unroll
        for (int mi = 0; mi < 8; mi++) {
          int kr = mi * 16 + l16;
          bf16x8_t kf = *(const bf16x8_t*)&Kc[kr * 64 + (((ks * 4 + quad) ^ (kr & 7)) * 8)];
          sacc[mi][0] = __builtin_amdgcn_mfma_f32_16x16x32_bf16(kf, qf[0][ks], sacc[mi][0], 0, 0, 0);
          sacc[mi][1] = __builtin_amdgcn_mfma_f32_16x16x32_bf16(kf, qf[1][ks], sacc[mi][1], 0, 0, 0);
        }

      if (kb == qb) {  // causal mask, block-local
#pragma unroll
        for (int mi = 0; mi < 8; mi++)
#pragma unroll
          for (int ni = 0; ni < 2; ni++) {
            int qrow = wave * 32 + ni * 16 + l16;
            int krow = mi * 16 + quad * 4;
#pragma unroll
            for (int r = 0; r < 4; r++)
              if (krow + r > qrow) sacc[mi][ni][r] = -1e30f;
          }
      }

      // online softmax (base-2; scale folded into Q). Tree-reduced in-lane stats
      // (dep depth ~9 vs 31) + 2 shuffles.
#pragma unroll
      for (int ni = 0; ni < 2; ni++) {
        f32x4_t t0 = vmax4(vmax4(sacc[0][ni], sacc[1][ni]),
                           vmax4(sacc[2][ni], sacc[3][ni]));
        f32x4_t t1 = vmax4(vmax4(sacc[4][ni], sacc[5][ni]),
                           vmax4(sacc[6][ni], sacc[7][ni]));
        t0 = vmax4(t0, t1);
        float mx = fmaxf(fmaxf(t0[0], t0[1]), fmaxf(t0[2], t0[3]));
        mx = fmaxf(mx, __shfl_xor(mx, 16));
        mx = fmaxf(mx, __shfl_xor(mx, 32));
        float mnew = fmaxf(m_[ni], mx);
        float alpha = __builtin_amdgcn_exp2f(m_[ni] - mnew);
        m_[ni] = mnew;
        f32x4_t a0 = {0.f, 0.f, 0.f, 0.f}, a1 = {0.f, 0.f, 0.f, 0.f};
#pragma unroll
        for (int mi = 0; mi < 4; mi++) {
#pragma unroll
          for (int r = 0; r < 4; r++) {
            sacc[mi][ni][r] = __builtin_amdgcn_exp2f(sacc[mi][ni][r] - mnew);
            sacc[mi + 4][ni][r] = __builtin_amdgcn_exp2f(sacc[mi + 4][ni][r] - mnew);
          }
          a0 += sacc[mi][ni];
          a1 += sacc[mi + 4][ni];
        }
        a0 += a1;
        float rs = (a0[0] + a0[1]) + (a0[2] + a0[3]);
        rs += __shfl_xor(rs, 16);
        rs += __shfl_xor(rs, 32);
        l_[ni] = alpha * l_[ni] + rs;
#pragma unroll
        for (int mi = 0; mi < 4; mi++)
#pragma unroll
          for (int r = 0; r < 4; r++) o[mi][ni][r] *= alpha;
      }

      // PV: O^T += Vt·P^T with k-permutation pi absorbed into V reads.
      // B-frag(f) element (quad, j) = sacc[2f + (j>>2)][ni][j&3]  (own lane!).
      // A-frag(f) element (quad, j) = V[d][s = (2f+(j>>2))*16 + quad*4 + (j&3)]:
      //   two b64 reads at s-groups g=4f+(quad>>1) and g+2, sub-half (quad&1).
#pragma unroll
      for (int f = 0; f < 4; f++) {
        bf16x8_t pb[2];
#pragma unroll
        for (int ni = 0; ni < 2; ni++)
#pragma unroll
          for (int r = 0; r < 4; r++) {
            pb[ni][r]     = (bf16)sacc[2 * f][ni][r];
            pb[ni][r + 4] = (bf16)sacc[2 * f + 1][ni][r];
          }
#pragma unroll
        for (int mi = 0; mi < 4; mi++) {
          int d = mi * 16 + l16;
          int e = d & 7;
          int g1 = 4 * f + (quad >> 1);
          const bf16* rp = Vc + d * 128 + (quad & 1) * 4;
          bf16x4_t lo = *(const bf16x4_t*)(rp + ((g1 ^ e) * 8));
          bf16x4_t hi = *(const bf16x4_t*)(rp + (((g1 + 2) ^ e) * 8));
          bf16x8_t vb = __builtin_shufflevector(lo, hi, 0, 1, 2, 3, 4, 5, 6, 7);
#pragma unroll
          for (int ni = 0; ni < 2; ni++)
            o[mi][ni] = __builtin_amdgcn_mfma_f32_16x16x32_bf16(vb, pb[ni], o[mi][ni], 0, 0, 0);
        }
      }

      __syncthreads();  // one barrier/tile: drains vmcnt(0) (next tile staged) and
                        // guards buffer reuse for all waves
      cur ^= 1;
    }

    // epilogue: O^T lane layout -> O[b][s][h*64+d], packed 4 consecutive d
#pragma unroll
    for (int ni = 0; ni < 2; ni++) {
      float inv = 1.0f / l_[ni];
      int q_g = qb * 128 + wave * 32 + ni * 16 + l16;
      size_t rowb = (size_t)(b * S_ + q_g) * E_ + h * HD;
#pragma unroll
      for (int mi = 0; mi < 4; mi++) {
        bf16x4_t ov;
#pragma unroll
        for (int r = 0; r < 4; r++) ov[r] = (bf16)(o[mi][ni][r] * inv);
        *(bf16x4_t*)&O[rowb + mi * 16 + quad * 4] = ov;
      }
    }
  }
}

extern "C" void kernel_launch(void* const* d_in, const int* in_sizes, int n_in,
                              void* d_out, int out_size, void* d_ws, size_t ws_size,
                              hipStream_t stream) {
  const float* x      = (const float*)d_in[0];
  const float* W_attn = (const float*)d_in[1];
  const float* b_attn = (const float*)d_in[2];
  const float* W_proj = (const float*)d_in[3];
  const float* b_proj = (const float*)d_in[4];
  float* out = (float*)d_out;

  // workspace (bf16 elems), ~75.5 MB total
  bf16* xb  = (bf16*)d_ws;            // 8192*1024
  bf16* Wat = xb + 8388608ull;        // 3072*1024 (W_attn^T)
  bf16* Wpt = Wat + 3145728ull;       // 1024*1024 (W_proj^T)
  bf16* Qb  = Wpt + 1048576ull;       // [B,H,S,64], pre-scaled by QSCALE
  bf16* Kb  = Qb + 8388608ull;        // [B,H,S,64]
  bf16* Vtb = Kb + 8388608ull;        // [B,H,64,S] (written transposed by QKV epilogue)
  bf16* AOb = xb;                     // alias: x dead after QKV GEMM

  prep<<<12288, 256, 0, stream>>>(x, xb, W_attn, Wat, W_proj, Wpt);
  gemm128<0><<<dim3(64, 24), 256, 0, stream>>>(xb, Wat, b_attn, Qb, Kb, Vtb, nullptr);
  attn_kernel<<<dim3(8, 64), 256, 65536, stream>>>(Qb, Kb, Vtb, AOb);
  gemm128<1><<<dim3(64, 8), 256, 0, stream>>>(AOb, Wpt, b_proj, nullptr, nullptr, nullptr, out);
}